// Round 1
// baseline (150.835 us; speedup 1.0000x reference)
//
#include <hip/hip_runtime.h>

// B=32, T=2048, D=64, K=4, KD=256
// out[b,t,j] = m*ha + (1-m)*(g*h_fwd + (1-g)*ha)
//   d = j % 64, m = M[b,t,d], delta = deltas[b,t,d] in {1,2,3,4} (clamped <= t+1)
//   g = exp(-relu(delta*W[j] + b[j]))
//   h_fwd = h_a[b, t-(int(delta)-1), j]  -> one of rows t, t-1, t-2, t-3
//
// v2: rolling-window register reuse. Each thread owns one float4 column and
// walks SEG=8 consecutive rows of one batch. Row t's ha4 becomes the next
// rows' gather candidate, so the t-1..t-3 candidates live in 3 rotating
// registers instead of being re-loaded from L1/L2 every row (v1 issued 9 VMEM
// instrs / 144B of L1 traffic per 16B output; v2 issues ~4.1 / ~54B, all
// fresh-stream). W/b loaded once per thread (fixed j0).

#define TD_T   2048
#define TD_KD  256
#define TD_D   64
#define SEG    8                   // rows per thread
#define SEGS_PER_B (TD_T / SEG)    // 256

typedef float f32x4 __attribute__((ext_vector_type(4)));

__global__ __launch_bounds__(256) void TemporalDecay_89524298318172_kernel(
    const float* __restrict__ h_a,
    const float* __restrict__ deltas,
    const float* __restrict__ M,
    const float* __restrict__ W,
    const float* __restrict__ bias,
    float* __restrict__ out)
{
    const int gid = blockIdx.x * blockDim.x + threadIdx.x;
    const int q   = gid & 63;            // float4 column within the 256-wide row
    const int wv  = gid >> 6;            // global wave = b * SEGS_PER_B + s
    const int s   = wv & (SEGS_PER_B - 1);
    const int b   = wv >> 8;             // wv / SEGS_PER_B (SEGS_PER_B == 256)
    const int t0  = s * SEG;
    const int j0  = q << 2;              // 0..252
    const int d0  = j0 & (TD_D - 1);     // no wrap inside a float4 (4 | 64)

    const size_t row0 = (size_t)(b * TD_T + t0);
    const float* __restrict__ ha_p = h_a    + row0 * TD_KD + j0;
    const float* __restrict__ m_p  = M      + row0 * TD_D  + d0;
    const float* __restrict__ dl_p = deltas + row0 * TD_D  + d0;
    float* __restrict__ o_p        = out    + row0 * TD_KD + j0;

    // Per-thread constants: one load each for the whole segment.
    const f32x4 w4 = *(const f32x4*)(W    + j0);
    const f32x4 b4 = *(const f32x4*)(bias + j0);

    // Rolling window = rows t0-1, t0-2, t0-3. First segment clamps to row 0;
    // those values are never selected because delta <= t+1 guarantees the
    // gathered row index is >= 0 (c_r selected only when t >= r).
    f32x4 c1 = *(const f32x4*)(ha_p - (t0 >= 1 ? 1 : 0) * TD_KD);
    f32x4 c2 = *(const f32x4*)(ha_p - (t0 >= 2 ? 2 : 0) * TD_KD);
    f32x4 c3 = *(const f32x4*)(ha_p - (t0 >= 3 ? 3 : 0) * TD_KD);

#pragma unroll 4
    for (int i = 0; i < SEG; ++i) {
        const f32x4 ha4 = *(const f32x4*)ha_p;
        const f32x4 m4  = *(const f32x4*)m_p;
        const f32x4 dl4 = *(const f32x4*)dl_p;

        f32x4 res;
#pragma unroll
        for (int e = 0; e < 4; ++e) {
            const float delta = dl4[e];
            const float g = __expf(-fmaxf(fmaf(delta, w4[e], b4[e]), 0.0f));
            // delta is an exact integer float in {1,2,3,4}; compares are exact
            float hf = ha4[e];
            hf = (delta > 1.5f) ? c1[e] : hf;
            hf = (delta > 2.5f) ? c2[e] : hf;
            hf = (delta > 3.5f) ? c3[e] : hf;
            const float m = m4[e];
            res[e] = m * ha4[e] + (1.0f - m) * (g * hf + (1.0f - g) * ha4[e]);
        }
        __builtin_nontemporal_store(res, (f32x4*)o_p);

        // rotate the candidate window
        c3 = c2; c2 = c1; c1 = ha4;
        ha_p += TD_KD; m_p += TD_D; dl_p += TD_D; o_p += TD_KD;
    }
}

extern "C" void kernel_launch(void* const* d_in, const int* in_sizes, int n_in,
                              void* d_out, int out_size, void* d_ws, size_t ws_size,
                              hipStream_t stream) {
    const float* h_a    = (const float*)d_in[0];
    const float* deltas = (const float*)d_in[1];
    const float* M      = (const float*)d_in[2];
    const float* W      = (const float*)d_in[3];
    const float* bias   = (const float*)d_in[4];
    float* out          = (float*)d_out;

    // in_sizes[0] = B*T*KD elements; rows = B*T = 65536
    const int rows = in_sizes[0] / TD_KD;
    const int total_threads = (rows / SEG) * 64;   // 524288
    const int block = 256;
    const int grid = total_threads / block;        // 2048
    TemporalDecay_89524298318172_kernel<<<grid, block, 0, stream>>>(
        h_a, deltas, M, W, bias, out);
}

// Round 2
// 146.150 us; speedup vs baseline: 1.0321x; 1.0321x over previous
//
#include <hip/hip_runtime.h>

// B=32, T=2048, D=64, K=4, KD=256
// out[b,t,j] = m*ha + (1-m)*(g*h_fwd + (1-g)*ha)
//   d = j % 64, m = M[b,t,d], delta = deltas[b,t,d] in {1,2,3,4} (clamped <= t+1)
//   g = exp(-relu(delta*W[j] + b[j]))
//   h_fwd = h_a[b, t-(int(delta)-1), j]  -> one of rows t, t-1, t-2, t-3
//
// v3: pair-of-rows per thread (rolling window at depth 2, no loop).
//  - Keeps v1's concurrency shape: short-lived waves, 8192 blocks (32/CU),
//    all loads issued up-front with no inter-load dependencies. v2's SEG=8
//    regression showed the machine is concurrency/latency-sensitive, not
//    VMEM-byte-sensitive alone; depth 2 halves redundant candidate loads
//    (row t+1's candidates = {ha0(reg), c1, c2}) without serialization.
//  - 11 loads + 2 stores / 176 B L1 traffic per 32 B output (v1: 20 / 304 B).
//  - VGPR must stay <= 64 (residency cliff at 64): 11 f32x4 live + temps.

#define TD_T   2048
#define TD_KD  256
#define TD_D   64

typedef float f32x4 __attribute__((ext_vector_type(4)));

__device__ __forceinline__ f32x4 td_row(const f32x4 ha, const f32x4 m4, const f32x4 dl4,
                                        const f32x4 c1, const f32x4 c2, const f32x4 c3,
                                        const f32x4 w4, const f32x4 b4)
{
    f32x4 res;
#pragma unroll
    for (int e = 0; e < 4; ++e) {
        const float delta = dl4[e];
        const float g = __expf(-fmaxf(fmaf(delta, w4[e], b4[e]), 0.0f));
        // delta is an exact small integer in float; compares are exact
        float hf = ha[e];
        hf = (delta > 1.5f) ? c1[e] : hf;
        hf = (delta > 2.5f) ? c2[e] : hf;
        hf = (delta > 3.5f) ? c3[e] : hf;
        const float m = m4[e];
        res[e] = m * ha[e] + (1.0f - m) * (g * hf + (1.0f - g) * ha[e]);
    }
    return res;
}

__global__ __launch_bounds__(256) void TemporalDecay_89524298318172_kernel(
    const float* __restrict__ h_a,
    const float* __restrict__ deltas,
    const float* __restrict__ M,
    const float* __restrict__ W,
    const float* __restrict__ bias,
    float* __restrict__ out)
{
    const int gid  = blockIdx.x * blockDim.x + threadIdx.x;
    const int q    = gid & 63;          // float4 column within the 256-wide row
    const int seg  = gid >> 6;          // row pair index; row0 = 2*seg
    const int row0 = seg << 1;
    const int t0   = row0 & (TD_T - 1); // even
    const int j0   = q << 2;            // 0..252
    const int d0   = j0 & (TD_D - 1);   // no wrap inside a float4 (4 | 64)

    const size_t off_kd = (size_t)row0 * TD_KD + j0;
    const size_t off_d  = (size_t)row0 * TD_D + d0;
    const float* __restrict__ hp = h_a + off_kd;

    // Per-thread constants
    const f32x4 w4 = *(const f32x4*)(W    + j0);
    const f32x4 b4 = *(const f32x4*)(bias + j0);

    // Candidate rows t0-1, t0-2, t0-3 (clamped; clamped values are never
    // selected because delta <= t+1 bounds the gathered row index >= 0).
    // t0 even: t0==0 -> all offsets 0; t0==2 -> o3 clamps to 0 (c3 unused
    // for row t0 since delta<=3 there; row t0+1's c3' = c2 = row 0, correct).
    const int o1 = (t0 >= 1) ? 1 : 0;
    const int o2 = (t0 >= 2) ? 2 : 0;
    const int o3 = (t0 >= 3) ? 3 : 0;
    const f32x4 c1 = *(const f32x4*)(hp - o1 * TD_KD);
    const f32x4 c2 = *(const f32x4*)(hp - o2 * TD_KD);
    const f32x4 c3 = *(const f32x4*)(hp - o3 * TD_KD);

    // Both rows' streams, all independent, issued together.
    const f32x4 ha0 = *(const f32x4*)hp;
    const f32x4 ha1 = *(const f32x4*)(hp + TD_KD);
    const f32x4 m0  = *(const f32x4*)(M + off_d);
    const f32x4 m1  = *(const f32x4*)(M + off_d + TD_D);
    const f32x4 dl0 = *(const f32x4*)(deltas + off_d);
    const f32x4 dl1 = *(const f32x4*)(deltas + off_d + TD_D);

    const f32x4 r0 = td_row(ha0, m0, dl0, c1,  c2, c3, w4, b4);
    const f32x4 r1 = td_row(ha1, m1, dl1, ha0, c1, c2, w4, b4);  // rolled window

    __builtin_nontemporal_store(r0, (f32x4*)(out + off_kd));
    __builtin_nontemporal_store(r1, (f32x4*)(out + off_kd + TD_KD));
}

extern "C" void kernel_launch(void* const* d_in, const int* in_sizes, int n_in,
                              void* d_out, int out_size, void* d_ws, size_t ws_size,
                              hipStream_t stream) {
    const float* h_a    = (const float*)d_in[0];
    const float* deltas = (const float*)d_in[1];
    const float* M      = (const float*)d_in[2];
    const float* W      = (const float*)d_in[3];
    const float* bias   = (const float*)d_in[4];
    float* out          = (float*)d_out;

    // in_sizes[0] = B*T*KD elements; rows = 65536; 2 rows per 64-lane segment
    const int rows = in_sizes[0] / TD_KD;
    const int total_threads = (rows / 2) * 64;     // 2,097,152
    const int block = 256;
    const int grid = total_threads / block;        // 8192
    TemporalDecay_89524298318172_kernel<<<grid, block, 0, stream>>>(
        h_a, deltas, M, W, bias, out);
}